// Round 10
// baseline (285.299 us; speedup 1.0000x reference)
//
#include <hip/hip_runtime.h>

// Seq2SeqLSTM: H=64, F=8, T=512, P=64, B=1024, fp32 in/out.
// R10 (base = R7, 202us): latency-chain cuts only.
//  (1) h-MFMA pair UNCHAINED: Qa=mfma(a0,w0,P), Qb=mfma(a1,w1,0), gate=Qa+Qb
//      -> the two MFMA latencies overlap (saves ~35 cyc of serial chain).
//  (2) fused-rcp cell algebra: si*tanh(g)=(eg-1)*rcp((1+ei)(1+eg));
//      so*tanh(c)=(ec-1)*rcp((1+eo)(1+ec)); 5 exp2 + 3 rcp (was 5+5),
//      shallower serial chain; cS clamped +-80 before exp2 (NaN guard).
//  (3) no A-row swizzle (R7 falsified the conflict theory).
// Topology: MB=4 over 256 blocks; lane (q,col) owns cell (batch q, unit
// wv*16+col); batch b at A-row 4b so C/D row=4q+0 puts gates in acc[.][0];
// fp16 weights/h/x pre-scaled by log2e (2*log2e for g-gate); 1 barrier/step.

#define Hh 64
#define Ff 8
#define Tt 512
#define Pp 64
#define BATCH 1024
#define MB 4
#define NBLK (BATCH / MB)   // 256 blocks
#define ROWS 72             // halves per A row (64 + 8 pad)
#define ABUF (16 * ROWS)
#define XSTRIDE 32          // halves per x step-row: 4 batches * 8

typedef __attribute__((ext_vector_type(8))) _Float16 half8;
typedef __attribute__((ext_vector_type(4))) _Float16 half4;
typedef __attribute__((ext_vector_type(4))) float f32x4;

#define LOG2E  1.44269504088896340736f
#define K2LOG2 2.88538008177792681472f   // 2*log2e

__device__ __forceinline__ float rcp_(float x)  { return __builtin_amdgcn_rcpf(x); }
__device__ __forceinline__ float exp2_(float x) { return __builtin_amdgcn_exp2f(x); }

// B-fragments: 4 gate tiles, fp16, log2e-pre-scaled (2*log2e for g-gate).
// B layout (16x16x32): lane holds B[k = kc*32 + q*8 + j][n = col].
__device__ __forceinline__ void load_wfrags(
    const float* __restrict__ Whh, const float* __restrict__ Wih,
    int wv, int q, int col, half8 w0[4], half8 w1[4], half8 wx[4])
{
    #pragma unroll
    for (int Tg = 0; Tg < 4; ++Tg) {
        int g = Tg * 64 + wv * 16 + col;
        float sc = (Tg == 2) ? K2LOG2 : LOG2E;
        const float* r0 = Whh + g * 64 + q * 8;
        #pragma unroll
        for (int j = 0; j < 8; ++j) {
            w0[Tg][j] = (_Float16)(r0[j] * sc);
            w1[Tg][j] = (_Float16)(r0[32 + j] * sc);
            wx[Tg][j] = (q == 0) ? (_Float16)(Wih[g * 8 + j] * sc) : (_Float16)0.f;
        }
    }
}

// P[Tg] = x-contribution + bias (C-init). Off the critical path (xs immutable).
__device__ __forceinline__ void pchain(half8 ax, const half8 wx[4],
                                       const f32x4 biasv[4], f32x4 P[4])
{
    P[2] = __builtin_amdgcn_mfma_f32_16x16x32_f16(ax, wx[2], biasv[2], 0, 0, 0);
    P[0] = __builtin_amdgcn_mfma_f32_16x16x32_f16(ax, wx[0], biasv[0], 0, 0, 0);
    P[1] = __builtin_amdgcn_mfma_f32_16x16x32_f16(ax, wx[1], biasv[1], 0, 0, 0);
    P[3] = __builtin_amdgcn_mfma_f32_16x16x32_f16(ax, wx[3], biasv[3], 0, 0, 0);
}

// Critical path: 8 INDEPENDENT MFMAs (4 pairs, depth 1) + fused-rcp cell.
__device__ __forceinline__ float qcell(half8 a0, half8 a1,
    const half8 w0[4], const half8 w1[4], const f32x4 P[4], float& cS)
{
    f32x4 z = {0.f, 0.f, 0.f, 0.f};
    f32x4 QgA = __builtin_amdgcn_mfma_f32_16x16x32_f16(a0, w0[2], P[2], 0, 0, 0);
    f32x4 QgB = __builtin_amdgcn_mfma_f32_16x16x32_f16(a1, w1[2], z,    0, 0, 0);
    f32x4 QiA = __builtin_amdgcn_mfma_f32_16x16x32_f16(a0, w0[0], P[0], 0, 0, 0);
    f32x4 QiB = __builtin_amdgcn_mfma_f32_16x16x32_f16(a1, w1[0], z,    0, 0, 0);
    f32x4 QfA = __builtin_amdgcn_mfma_f32_16x16x32_f16(a0, w0[1], P[1], 0, 0, 0);
    f32x4 QfB = __builtin_amdgcn_mfma_f32_16x16x32_f16(a1, w1[1], z,    0, 0, 0);
    f32x4 QoA = __builtin_amdgcn_mfma_f32_16x16x32_f16(a0, w0[3], P[3], 0, 0, 0);
    f32x4 QoB = __builtin_amdgcn_mfma_f32_16x16x32_f16(a1, w1[3], z,    0, 0, 0);

    float Qg = QgA[0] + QgB[0];          // 2*log2e-scaled g pre-act
    float Qi = QiA[0] + QiB[0];          // log2e-scaled
    float Qf = QfA[0] + QfB[0];
    float Qo = QoA[0] + QoB[0];

    float eg = exp2_(Qg);                // e^{2g}
    float ei = exp2_(-Qi);
    float ef = exp2_(-Qf);
    float eo = exp2_(-Qo);
    // si*tanh(g) = (eg-1) * rcp((1+ei)*(1+eg))
    float it = (eg - 1.f) * rcp_((1.f + ei) * (1.f + eg));
    float sf = rcp_(1.f + ef);
    cS = __builtin_fmaf(sf, cS, K2LOG2 * it);          // cS = 2*log2e * c
    float cc = fminf(fmaxf(cS, -80.f), 80.f);          // overflow guard for exp2
    float ec = exp2_(cc);                               // e^{2c}
    // so*tanh(c) = (ec-1) * rcp((1+eo)*(1+ec))
    return (ec - 1.f) * rcp_((1.f + eo) * (1.f + ec));
}

__global__ __launch_bounds__(256, 1)
void seq2seq_v10(const float* __restrict__ x_seq,
                 const float* __restrict__ eWih, const float* __restrict__ eWhh,
                 const float* __restrict__ ebih, const float* __restrict__ ebhh,
                 const float* __restrict__ dWih, const float* __restrict__ dWhh,
                 const float* __restrict__ dbih, const float* __restrict__ dbhh,
                 const float* __restrict__ fcW,  const float* __restrict__ fcb,
                 float* __restrict__ out)
{
    __shared__ __align__(16) _Float16 xs[(Tt + 2) * XSTRIDE];  // 32.9 KB; predbuf alias
    __shared__ __align__(16) _Float16 A0[ABUF];
    __shared__ __align__(16) _Float16 A1[ABUF];
    __shared__ float fcWT[Hh * 9 + 8];
    __shared__ float sfcb[Ff];
    __shared__ __align__(16) _Float16 xdec[MB * Ff];

    const int tid  = threadIdx.x;
    const int wv   = tid >> 6;
    const int lane = tid & 63;
    const int q    = lane >> 4;
    const int col  = lane & 15;
    const int u    = wv * 16 + col;
    const int b0   = blockIdx.x * MB;

    half8 w0[4], w1[4], wx[4];
    load_wfrags(eWhh, eWih, wv, q, col, w0, w1, wx);
    f32x4 biasv[4];
    #pragma unroll
    for (int Tg = 0; Tg < 4; ++Tg) {
        int g = Tg * 64 + u;
        float sc = (Tg == 2) ? K2LOG2 : LOG2E;
        float bv = (ebih[g] + ebhh[g]) * sc;
        biasv[Tg] = (f32x4){bv, bv, bv, bv};
    }

    // init: zero A buffers + xs pad rows, stage fc weights + x (fp32 -> fp16)
    { int* Z0 = (int*)A0; int* Z1 = (int*)A1;
      for (int i = tid; i < ABUF / 2; i += 256) { Z0[i] = 0; Z1[i] = 0; } }
    for (int i = tid; i < Ff * Hh; i += 256) { int f = i >> 6, uu = i & 63; fcWT[uu * 9 + f] = fcW[i]; }
    if (tid < Ff) sfcb[tid] = fcb[tid];
    if (tid < 32) ((int*)xs)[Tt * 16 + tid] = 0;         // zero 2 pad rows
    for (int i = tid; i < MB * Tt * 2; i += 256) {       // 4096 float4s
        int b   = i >> 10;
        int rem = i & 1023;
        int t   = rem >> 1;
        int f4  = (rem & 1) * 4;
        const float* src = x_seq + ((size_t)(b0 + b) * Tt + t) * Ff + f4;
        half4 s = { (_Float16)src[0], (_Float16)src[1], (_Float16)src[2], (_Float16)src[3] };
        *(half4*)(&xs[t * XSTRIDE + b * 8 + f4]) = s;
    }
    __syncthreads();                                     // staging visible

    // per-lane hoisted pointers (no swizzle)
    const _Float16* arA = A0 + col * ROWS + q * 8;
    const _Float16* arB = A1 + col * ROWS + q * 8;
    _Float16* hwA = A0 + 4 * q * ROWS + u;
    _Float16* hwB = A1 + 4 * q * ROWS + u;
    const _Float16* xq = xs + (col >> 2) * 8;            // x walker (broadcast groups)

    float cS = 0.f;
    f32x4 P[4];
    {   half8 ax = *(const half8*)(xq);                  // x(0)
        pchain(ax, wx, biasv, P);                        // P for step 0
        xq += XSTRIDE; }

    // ============ encoder: 512 steps, barrier at top, P one step ahead ============
    for (int t = 0; t < Tt; t += 2) {
        __syncthreads();                                 // h(t) visible (A0)
        {
            half8 ax = *(const half8*)(xq); xq += XSTRIDE;   // x(t+1), off-CP
            half8 a0 = *(const half8*)(arA);
            half8 a1 = *(const half8*)(arA + 32);
            float hn = qcell(a0, a1, w0, w1, P, cS);
            *hwB = (_Float16)hn;                         // h(t+1) -> A1
            pchain(ax, wx, biasv, P);                    // P for t+1 (shadow)
        }
        __syncthreads();                                 // h(t+1) visible (A1)
        {
            half8 ax = *(const half8*)(xq); xq += XSTRIDE;   // x(t+2) (pad rows at end)
            half8 a0 = *(const half8*)(arB);
            half8 a1 = *(const half8*)(arB + 32);
            float hn = qcell(a0, a1, w0, w1, P, cS);
            *hwA = (_Float16)hn;                         // h(t+2) -> A0
            pchain(ax, wx, biasv, P);                    // P for t+2 (shadow)
        }
    }
    // after loop: h(512) in A0.

    // ================= decoder setup =================
    load_wfrags(dWhh, dWih, wv, q, col, w0, w1, wx);
    #pragma unroll
    for (int Tg = 0; Tg < 4; ++Tg) {
        int g = Tg * 64 + u;
        float sc = (Tg == 2) ? K2LOG2 : LOG2E;
        float bv = (dbih[g] + dbhh[g]) * sc;
        biasv[Tg] = (f32x4){bv, bv, bv, bv};
    }
    if (tid < MB * Ff) xdec[tid] = xs[(Tt - 1) * XSTRIDE + tid];   // x_dec(0)=x[:,T-1]
    __syncthreads();                                     // h(512) + xdec visible

    float* predbuf = (float*)xs;                         // 8 KB alias over dead xs
    const _Float16* xdp = xdec + (col >> 2) * 8;

    // ============ decoder: 64 steps (A0 -> A1 -> ...), fc + feedback ============
    for (int p = 0; p < Pp; ++p) {
        const _Float16* ar = (p & 1) ? arB : arA;
        _Float16*       hw = (p & 1) ? hwA : hwB;
        const _Float16* hb = (p & 1) ? A0  : A1;         // buffer written this step
        half8 ax = *(const half8*)(xdp);
        pchain(ax, wx, biasv, P);
        half8 a0 = *(const half8*)(ar);
        half8 a1 = *(const half8*)(ar + 32);
        float hn = qcell(a0, a1, w0, w1, P, cS);
        *hw = (_Float16)hn;
        __syncthreads();
        if (tid < MB * Ff) {
            int b = tid >> 3, f = tid & 7;
            const _Float16* hr = hb + (4 * b) * ROWS;
            float s = sfcb[f];
            #pragma unroll
            for (int ch = 0; ch < 8; ++ch) {
                half8 hh = *(const half8*)(hr + ch * 8);
                #pragma unroll
                for (int j = 0; j < 8; ++j)
                    s += (float)hh[j] * fcWT[(ch * 8 + j) * 9 + f];
            }
            predbuf[b * (Pp * Ff) + p * Ff + f] = s;
            xdec[tid] = (_Float16)s;
        }
        __syncthreads();
    }

    // ================= flush preds: LDS -> global, coalesced float4 =================
    {
        f32x4* out4 = (f32x4*)out + (size_t)b0 * (Pp * Ff / 4);
        const f32x4* pb4 = (const f32x4*)predbuf;
        for (int i = tid; i < MB * Pp * Ff / 4; i += 256)
            out4[i] = pb4[i];
    }
}

extern "C" void kernel_launch(void* const* d_in, const int* in_sizes, int n_in,
                              void* d_out, int out_size, void* d_ws, size_t ws_size,
                              hipStream_t stream) {
    (void)in_sizes; (void)n_in; (void)d_ws; (void)ws_size; (void)out_size;
    hipLaunchKernelGGL(seq2seq_v10, dim3(NBLK), dim3(256), 0, stream,
                       (const float*)d_in[0],
                       (const float*)d_in[1], (const float*)d_in[2],
                       (const float*)d_in[3], (const float*)d_in[4],
                       (const float*)d_in[5], (const float*)d_in[6],
                       (const float*)d_in[7], (const float*)d_in[8],
                       (const float*)d_in[9], (const float*)d_in[10],
                       (float*)d_out);
}

// Round 11
// 261.073 us; speedup vs baseline: 1.0928x; 1.0928x over previous
//
#include <hip/hip_runtime.h>

// Seq2SeqLSTM: H=64, F=8, T=512, P=64, B=1024, fp32 in/out.
// R11 = R7 champion (202us) + ONE isolated change: fused-rcp cell algebra
// (8 trans ops, was 10; shallower serial chain) with MFMA structure untouched
// (chained depth-2 Q with C=P, pchain in shadow, A-row swizzle, 1 barrier/step).
//  si*tanh(g) = (eg-1)*rcp((1+ei)(1+eg));  so*tanh(c) = (ec-1)*rcp((1+eo)(1+ec));
//  cS clamped +-60 before exp2 (guards inf*0=NaN of the fused form; R10-validated).
// Topology: MB=4 over 256 blocks; lane (q,col) owns cell (batch q, unit
// wv*16+col); batch b at A-row 4b so C/D row=4q+0 puts gates in acc[.][0];
// fp16 weights/h/x pre-scaled by log2e (2*log2e for g-gate).

#define Hh 64
#define Ff 8
#define Tt 512
#define Pp 64
#define BATCH 1024
#define MB 4
#define NBLK (BATCH / MB)   // 256 blocks
#define ROWS 72             // halves per A row (64 + 8 pad)
#define ABUF (16 * ROWS + 64)
#define XSTRIDE 32          // halves per x step-row: 4 batches * 8

typedef __attribute__((ext_vector_type(8))) _Float16 half8;
typedef __attribute__((ext_vector_type(4))) _Float16 half4;
typedef __attribute__((ext_vector_type(4))) float f32x4;

#define LOG2E  1.44269504088896340736f
#define K2LOG2 2.88538008177792681472f   // 2*log2e

__device__ __forceinline__ float rcp_(float x)  { return __builtin_amdgcn_rcpf(x); }
__device__ __forceinline__ float exp2_(float x) { return __builtin_amdgcn_exp2f(x); }
// A-row swizzle (halves): rows 4b (writers) keep offset 0.
__device__ __forceinline__ int arow_base(int m) { return m * ROWS + (m & 3) * 16; }

// B-fragments: 4 gate tiles, fp16, log2e-pre-scaled (2*log2e for g-gate).
// B layout (16x16x32): lane holds B[k = kc*32 + q*8 + j][n = col].
__device__ __forceinline__ void load_wfrags(
    const float* __restrict__ Whh, const float* __restrict__ Wih,
    int wv, int q, int col, half8 w0[4], half8 w1[4], half8 wx[4])
{
    #pragma unroll
    for (int Tg = 0; Tg < 4; ++Tg) {
        int g = Tg * 64 + wv * 16 + col;
        float sc = (Tg == 2) ? K2LOG2 : LOG2E;
        const float* r0 = Whh + g * 64 + q * 8;
        #pragma unroll
        for (int j = 0; j < 8; ++j) {
            w0[Tg][j] = (_Float16)(r0[j] * sc);
            w1[Tg][j] = (_Float16)(r0[32 + j] * sc);
            wx[Tg][j] = (q == 0) ? (_Float16)(Wih[g * 8 + j] * sc) : (_Float16)0.f;
        }
    }
}

// P[Tg] = x-contribution + bias (C-init). Off the critical path (xs immutable).
__device__ __forceinline__ void pchain(half8 ax, const half8 wx[4],
                                       const f32x4 biasv[4], f32x4 P[4])
{
    P[2] = __builtin_amdgcn_mfma_f32_16x16x32_f16(ax, wx[2], biasv[2], 0, 0, 0);
    P[0] = __builtin_amdgcn_mfma_f32_16x16x32_f16(ax, wx[0], biasv[0], 0, 0, 0);
    P[1] = __builtin_amdgcn_mfma_f32_16x16x32_f16(ax, wx[1], biasv[1], 0, 0, 0);
    P[3] = __builtin_amdgcn_mfma_f32_16x16x32_f16(ax, wx[3], biasv[3], 0, 0, 0);
}

// Critical path: 8 MFMA (4 chains depth 2, gate order g,i,f,o) + fused-rcp cell.
__device__ __forceinline__ float qcell(half8 a0, half8 a1,
    const half8 w0[4], const half8 w1[4], const f32x4 P[4], float& cS)
{
    f32x4 Qg = __builtin_amdgcn_mfma_f32_16x16x32_f16(a0, w0[2], P[2], 0, 0, 0);
    f32x4 Qi = __builtin_amdgcn_mfma_f32_16x16x32_f16(a0, w0[0], P[0], 0, 0, 0);
    f32x4 Qf = __builtin_amdgcn_mfma_f32_16x16x32_f16(a0, w0[1], P[1], 0, 0, 0);
    f32x4 Qo = __builtin_amdgcn_mfma_f32_16x16x32_f16(a0, w0[3], P[3], 0, 0, 0);
    Qg = __builtin_amdgcn_mfma_f32_16x16x32_f16(a1, w1[2], Qg, 0, 0, 0);
    Qi = __builtin_amdgcn_mfma_f32_16x16x32_f16(a1, w1[0], Qi, 0, 0, 0);
    Qf = __builtin_amdgcn_mfma_f32_16x16x32_f16(a1, w1[1], Qf, 0, 0, 0);
    Qo = __builtin_amdgcn_mfma_f32_16x16x32_f16(a1, w1[3], Qo, 0, 0, 0);

    float eg = exp2_(Qg[0]);             // e^{2g} (g-row pre-scaled 2*log2e)
    float ei = exp2_(-Qi[0]);
    float ef = exp2_(-Qf[0]);
    float eo = exp2_(-Qo[0]);
    // si*tanh(g) = (eg-1) * rcp((1+ei)*(1+eg))
    float it = (eg - 1.f) * rcp_((1.f + ei) * (1.f + eg));
    float sf = rcp_(1.f + ef);
    cS = __builtin_fmaf(sf, cS, K2LOG2 * it);          // cS = 2*log2e * c
    float cc = fminf(fmaxf(cS, -60.f), 60.f);          // exp2 overflow guard
    float ec = exp2_(cc);                               // e^{2c}
    // so*tanh(c) = (ec-1) * rcp((1+eo)*(1+ec))
    return (ec - 1.f) * rcp_((1.f + eo) * (1.f + ec));
}

__global__ __launch_bounds__(256, 1)
void seq2seq_v11(const float* __restrict__ x_seq,
                 const float* __restrict__ eWih, const float* __restrict__ eWhh,
                 const float* __restrict__ ebih, const float* __restrict__ ebhh,
                 const float* __restrict__ dWih, const float* __restrict__ dWhh,
                 const float* __restrict__ dbih, const float* __restrict__ dbhh,
                 const float* __restrict__ fcW,  const float* __restrict__ fcb,
                 float* __restrict__ out)
{
    __shared__ __align__(16) _Float16 xs[(Tt + 2) * XSTRIDE];  // 32.9 KB; predbuf alias
    __shared__ __align__(16) _Float16 A0[ABUF];
    __shared__ __align__(16) _Float16 A1[ABUF];
    __shared__ float fcWT[Hh * 9 + 8];
    __shared__ float sfcb[Ff];
    __shared__ __align__(16) _Float16 xdec[MB * Ff];

    const int tid  = threadIdx.x;
    const int wv   = tid >> 6;
    const int lane = tid & 63;
    const int q    = lane >> 4;
    const int col  = lane & 15;
    const int u    = wv * 16 + col;
    const int b0   = blockIdx.x * MB;

    half8 w0[4], w1[4], wx[4];
    load_wfrags(eWhh, eWih, wv, q, col, w0, w1, wx);
    f32x4 biasv[4];
    #pragma unroll
    for (int Tg = 0; Tg < 4; ++Tg) {
        int g = Tg * 64 + u;
        float sc = (Tg == 2) ? K2LOG2 : LOG2E;
        float bv = (ebih[g] + ebhh[g]) * sc;
        biasv[Tg] = (f32x4){bv, bv, bv, bv};
    }

    // init: zero A buffers + xs pad rows, stage fc weights + x (fp32 -> fp16)
    { int* Z0 = (int*)A0; int* Z1 = (int*)A1;
      for (int i = tid; i < ABUF / 2; i += 256) { Z0[i] = 0; Z1[i] = 0; } }
    for (int i = tid; i < Ff * Hh; i += 256) { int f = i >> 6, uu = i & 63; fcWT[uu * 9 + f] = fcW[i]; }
    if (tid < Ff) sfcb[tid] = fcb[tid];
    if (tid < 32) ((int*)xs)[Tt * 16 + tid] = 0;         // zero 2 pad rows
    for (int i = tid; i < MB * Tt * 2; i += 256) {       // 4096 float4s
        int b   = i >> 10;
        int rem = i & 1023;
        int t   = rem >> 1;
        int f4  = (rem & 1) * 4;
        const float* src = x_seq + ((size_t)(b0 + b) * Tt + t) * Ff + f4;
        half4 s = { (_Float16)src[0], (_Float16)src[1], (_Float16)src[2], (_Float16)src[3] };
        *(half4*)(&xs[t * XSTRIDE + b * 8 + f4]) = s;
    }
    __syncthreads();                                     // staging visible

    // per-lane hoisted pointers (swizzled A reads; writers at rows 4b, swizzle 0)
    const _Float16* arA = A0 + arow_base(col) + q * 8;
    const _Float16* arB = A1 + arow_base(col) + q * 8;
    _Float16* hwA = A0 + 4 * q * ROWS + u;
    _Float16* hwB = A1 + 4 * q * ROWS + u;
    const _Float16* xq = xs + (col >> 2) * 8;            // x walker (broadcast groups)

    float cS = 0.f;
    f32x4 P[4];
    {   half8 ax = *(const half8*)(xq);                  // x(0)
        pchain(ax, wx, biasv, P);                        // P for step 0
        xq += XSTRIDE; }

    // ============ encoder: 512 steps, barrier at top, P one step ahead ============
    for (int t = 0; t < Tt; t += 2) {
        __syncthreads();                                 // h(t) visible (A0)
        {
            half8 ax = *(const half8*)(xq); xq += XSTRIDE;   // x(t+1), off-CP
            half8 a0 = *(const half8*)(arA);
            half8 a1 = *(const half8*)(arA + 32);
            float hn = qcell(a0, a1, w0, w1, P, cS);
            *hwB = (_Float16)hn;                         // h(t+1) -> A1
            pchain(ax, wx, biasv, P);                    // P for t+1 (shadow)
        }
        __syncthreads();                                 // h(t+1) visible (A1)
        {
            half8 ax = *(const half8*)(xq); xq += XSTRIDE;   // x(t+2) (pad rows at end)
            half8 a0 = *(const half8*)(arB);
            half8 a1 = *(const half8*)(arB + 32);
            float hn = qcell(a0, a1, w0, w1, P, cS);
            *hwA = (_Float16)hn;                         // h(t+2) -> A0
            pchain(ax, wx, biasv, P);                    // P for t+2 (shadow)
        }
    }
    // after loop: h(512) in A0.

    // ================= decoder setup =================
    load_wfrags(dWhh, dWih, wv, q, col, w0, w1, wx);
    #pragma unroll
    for (int Tg = 0; Tg < 4; ++Tg) {
        int g = Tg * 64 + u;
        float sc = (Tg == 2) ? K2LOG2 : LOG2E;
        float bv = (dbih[g] + dbhh[g]) * sc;
        biasv[Tg] = (f32x4){bv, bv, bv, bv};
    }
    if (tid < MB * Ff) xdec[tid] = xs[(Tt - 1) * XSTRIDE + tid];   // x_dec(0)=x[:,T-1]
    __syncthreads();                                     // h(512) + xdec visible

    float* predbuf = (float*)xs;                         // 8 KB alias over dead xs
    const _Float16* xdp = xdec + (col >> 2) * 8;

    // ============ decoder: 64 steps (A0 -> A1 -> ...), fc + feedback ============
    for (int p = 0; p < Pp; ++p) {
        const _Float16* ar = (p & 1) ? arB : arA;
        _Float16*       hw = (p & 1) ? hwA : hwB;
        const _Float16* hb = (p & 1) ? A0  : A1;         // buffer written this step
        half8 ax = *(const half8*)(xdp);
        pchain(ax, wx, biasv, P);
        half8 a0 = *(const half8*)(ar);
        half8 a1 = *(const half8*)(ar + 32);
        float hn = qcell(a0, a1, w0, w1, P, cS);
        *hw = (_Float16)hn;
        __syncthreads();
        if (tid < MB * Ff) {
            int b = tid >> 3, f = tid & 7;
            const _Float16* hr = hb + (4 * b) * ROWS;
            float s = sfcb[f];
            #pragma unroll
            for (int ch = 0; ch < 8; ++ch) {
                half8 hh = *(const half8*)(hr + ch * 8);
                #pragma unroll
                for (int j = 0; j < 8; ++j)
                    s += (float)hh[j] * fcWT[(ch * 8 + j) * 9 + f];
            }
            predbuf[b * (Pp * Ff) + p * Ff + f] = s;
            xdec[tid] = (_Float16)s;
        }
        __syncthreads();
    }

    // ================= flush preds: LDS -> global, coalesced float4 =================
    {
        f32x4* out4 = (f32x4*)out + (size_t)b0 * (Pp * Ff / 4);
        const f32x4* pb4 = (const f32x4*)predbuf;
        for (int i = tid; i < MB * Pp * Ff / 4; i += 256)
            out4[i] = pb4[i];
    }
}

extern "C" void kernel_launch(void* const* d_in, const int* in_sizes, int n_in,
                              void* d_out, int out_size, void* d_ws, size_t ws_size,
                              hipStream_t stream) {
    (void)in_sizes; (void)n_in; (void)d_ws; (void)ws_size; (void)out_size;
    hipLaunchKernelGGL(seq2seq_v11, dim3(NBLK), dim3(256), 0, stream,
                       (const float*)d_in[0],
                       (const float*)d_in[1], (const float*)d_in[2],
                       (const float*)d_in[3], (const float*)d_in[4],
                       (const float*)d_in[5], (const float*)d_in[6],
                       (const float*)d_in[7], (const float*)d_in[8],
                       (const float*)d_in[9], (const float*)d_in[10],
                       (float*)d_out);
}

// Round 12
// 219.796 us; speedup vs baseline: 1.2980x; 1.1878x over previous
//
#include <hip/hip_runtime.h>

// Seq2SeqLSTM: H=64, F=8, T=512, P=64, B=1024, fp32 in/out.
// R12 = R11 encoder (unchanged, champion) + DECODER FOLD:
//   x_p = pred_{p-1} = fc(H_p)  =>  gates = H_p*(Whh + Wih*fcW)^T + (b + Wih*fcb)
// -> decoder is a pure h-recurrence (no xdec exchange, no serial fc, ONE
//    barrier/step; step CP == encoder CP minus pchain). pred is a pure output:
//    2 shadow fc-MFMAs (a0/a1 already read) -> predbuf, off the chain.
//    Step 0 uses the plain path (x = x_seq[:,T-1]); epilogue emits pred(63).
// Topology: MB=4 over 256 blocks; lane (q,col) owns cell (batch q, unit
// wv*16+col); batch b at A-row 4b so C/D row=4q+0 puts gates in acc[.][0];
// fp16 weights/h/x pre-scaled by log2e (2*log2e for g-gate); fused-rcp cell.

#define Hh 64
#define Ff 8
#define Tt 512
#define Pp 64
#define BATCH 1024
#define MB 4
#define NBLK (BATCH / MB)   // 256 blocks
#define ROWS 72             // halves per A row (64 + 8 pad)
#define ABUF (16 * ROWS + 64)
#define XSTRIDE 32          // halves per x step-row: 4 batches * 8

typedef __attribute__((ext_vector_type(8))) _Float16 half8;
typedef __attribute__((ext_vector_type(4))) _Float16 half4;
typedef __attribute__((ext_vector_type(4))) float f32x4;

#define LOG2E  1.44269504088896340736f
#define K2LOG2 2.88538008177792681472f   // 2*log2e

__device__ __forceinline__ float rcp_(float x)  { return __builtin_amdgcn_rcpf(x); }
__device__ __forceinline__ float exp2_(float x) { return __builtin_amdgcn_exp2f(x); }
// A-row swizzle (halves): rows 4b (writers) keep offset 0.
__device__ __forceinline__ int arow_base(int m) { return m * ROWS + (m & 3) * 16; }

// B-fragments: 4 gate tiles, fp16, log2e-pre-scaled (2*log2e for g-gate).
// B layout (16x16x32): lane holds B[k = kc*32 + q*8 + j][n = col].
__device__ __forceinline__ void load_wfrags(
    const float* __restrict__ Whh, const float* __restrict__ Wih,
    int wv, int q, int col, half8 w0[4], half8 w1[4], half8 wx[4])
{
    #pragma unroll
    for (int Tg = 0; Tg < 4; ++Tg) {
        int g = Tg * 64 + wv * 16 + col;
        float sc = (Tg == 2) ? K2LOG2 : LOG2E;
        const float* r0 = Whh + g * 64 + q * 8;
        #pragma unroll
        for (int j = 0; j < 8; ++j) {
            w0[Tg][j] = (_Float16)(r0[j] * sc);
            w1[Tg][j] = (_Float16)(r0[32 + j] * sc);
            wx[Tg][j] = (q == 0) ? (_Float16)(Wih[g * 8 + j] * sc) : (_Float16)0.f;
        }
    }
}

// P[Tg] = x-contribution + bias (C-init). Off the critical path.
__device__ __forceinline__ void pchain(half8 ax, const half8 wx[4],
                                       const f32x4 biasv[4], f32x4 P[4])
{
    P[2] = __builtin_amdgcn_mfma_f32_16x16x32_f16(ax, wx[2], biasv[2], 0, 0, 0);
    P[0] = __builtin_amdgcn_mfma_f32_16x16x32_f16(ax, wx[0], biasv[0], 0, 0, 0);
    P[1] = __builtin_amdgcn_mfma_f32_16x16x32_f16(ax, wx[1], biasv[1], 0, 0, 0);
    P[3] = __builtin_amdgcn_mfma_f32_16x16x32_f16(ax, wx[3], biasv[3], 0, 0, 0);
}

// Critical path: 8 MFMA (4 chains depth 2, gate order g,i,f,o) + fused-rcp cell.
__device__ __forceinline__ float qcell(half8 a0, half8 a1,
    const half8 w0[4], const half8 w1[4], const f32x4 P[4], float& cS)
{
    f32x4 Qg = __builtin_amdgcn_mfma_f32_16x16x32_f16(a0, w0[2], P[2], 0, 0, 0);
    f32x4 Qi = __builtin_amdgcn_mfma_f32_16x16x32_f16(a0, w0[0], P[0], 0, 0, 0);
    f32x4 Qf = __builtin_amdgcn_mfma_f32_16x16x32_f16(a0, w0[1], P[1], 0, 0, 0);
    f32x4 Qo = __builtin_amdgcn_mfma_f32_16x16x32_f16(a0, w0[3], P[3], 0, 0, 0);
    Qg = __builtin_amdgcn_mfma_f32_16x16x32_f16(a1, w1[2], Qg, 0, 0, 0);
    Qi = __builtin_amdgcn_mfma_f32_16x16x32_f16(a1, w1[0], Qi, 0, 0, 0);
    Qf = __builtin_amdgcn_mfma_f32_16x16x32_f16(a1, w1[1], Qf, 0, 0, 0);
    Qo = __builtin_amdgcn_mfma_f32_16x16x32_f16(a1, w1[3], Qo, 0, 0, 0);

    float eg = exp2_(Qg[0]);             // e^{2g} (g-row pre-scaled 2*log2e)
    float ei = exp2_(-Qi[0]);
    float ef = exp2_(-Qf[0]);
    float eo = exp2_(-Qo[0]);
    float it = (eg - 1.f) * rcp_((1.f + ei) * (1.f + eg));   // si*tanh(g)
    float sf = rcp_(1.f + ef);
    cS = __builtin_fmaf(sf, cS, K2LOG2 * it);                // cS = 2*log2e * c
    float cc = fminf(fmaxf(cS, -60.f), 60.f);                // exp2 overflow guard
    float ec = exp2_(cc);                                     // e^{2c}
    return (ec - 1.f) * rcp_((1.f + eo) * (1.f + ec));       // so*tanh(c)
}

__global__ __launch_bounds__(256, 1)
void seq2seq_v12(const float* __restrict__ x_seq,
                 const float* __restrict__ eWih, const float* __restrict__ eWhh,
                 const float* __restrict__ ebih, const float* __restrict__ ebhh,
                 const float* __restrict__ dWih, const float* __restrict__ dWhh,
                 const float* __restrict__ dbih, const float* __restrict__ dbhh,
                 const float* __restrict__ fcW,  const float* __restrict__ fcb,
                 float* __restrict__ out)
{
    __shared__ __align__(16) _Float16 xs[(Tt + 2) * XSTRIDE];  // 32.9 KB; predbuf alias
    __shared__ __align__(16) _Float16 A0[ABUF];
    __shared__ __align__(16) _Float16 A1[ABUF];

    const int tid  = threadIdx.x;
    const int wv   = tid >> 6;
    const int lane = tid & 63;
    const int q    = lane >> 4;
    const int col  = lane & 15;
    const int u    = wv * 16 + col;
    const int b0   = blockIdx.x * MB;

    half8 w0[4], w1[4], wx[4];
    load_wfrags(eWhh, eWih, wv, q, col, w0, w1, wx);
    f32x4 biasv[4];
    #pragma unroll
    for (int Tg = 0; Tg < 4; ++Tg) {
        int g = Tg * 64 + u;
        float sc = (Tg == 2) ? K2LOG2 : LOG2E;
        float bv = (ebih[g] + ebhh[g]) * sc;
        biasv[Tg] = (f32x4){bv, bv, bv, bv};
    }

    // init: zero A buffers + xs pad rows, stage x (fp32 -> fp16)
    { int* Z0 = (int*)A0; int* Z1 = (int*)A1;
      for (int i = tid; i < ABUF / 2; i += 256) { Z0[i] = 0; Z1[i] = 0; } }
    if (tid < 32) ((int*)xs)[Tt * 16 + tid] = 0;         // zero 2 pad rows
    for (int i = tid; i < MB * Tt * 2; i += 256) {       // 4096 float4s
        int b   = i >> 10;
        int rem = i & 1023;
        int t   = rem >> 1;
        int f4  = (rem & 1) * 4;
        const float* src = x_seq + ((size_t)(b0 + b) * Tt + t) * Ff + f4;
        half4 s = { (_Float16)src[0], (_Float16)src[1], (_Float16)src[2], (_Float16)src[3] };
        *(half4*)(&xs[t * XSTRIDE + b * 8 + f4]) = s;
    }
    __syncthreads();                                     // staging visible

    // per-lane hoisted pointers (swizzled A reads; writers at rows 4b, swizzle 0)
    const _Float16* arA = A0 + arow_base(col) + q * 8;
    const _Float16* arB = A1 + arow_base(col) + q * 8;
    _Float16* hwA = A0 + 4 * q * ROWS + u;
    _Float16* hwB = A1 + 4 * q * ROWS + u;
    const _Float16* xq = xs + (col >> 2) * 8;            // x walker (broadcast groups)

    float cS = 0.f;
    f32x4 P[4];
    {   half8 ax = *(const half8*)(xq);                  // x(0)
        pchain(ax, wx, biasv, P);                        // P for step 0
        xq += XSTRIDE; }

    // ============ encoder: 512 steps, barrier at top, P one step ahead ============
    for (int t = 0; t < Tt; t += 2) {
        __syncthreads();                                 // h(t) visible (A0)
        {
            half8 ax = *(const half8*)(xq); xq += XSTRIDE;   // x(t+1), off-CP
            half8 a0 = *(const half8*)(arA);
            half8 a1 = *(const half8*)(arA + 32);
            float hn = qcell(a0, a1, w0, w1, P, cS);
            *hwB = (_Float16)hn;                         // h(t+1) -> A1
            pchain(ax, wx, biasv, P);                    // P for t+1 (shadow)
        }
        __syncthreads();                                 // h(t+1) visible (A1)
        {
            half8 ax = *(const half8*)(xq); xq += XSTRIDE;   // x(t+2) (pad rows at end)
            half8 a0 = *(const half8*)(arB);
            half8 a1 = *(const half8*)(arB + 32);
            float hn = qcell(a0, a1, w0, w1, P, cS);
            *hwA = (_Float16)hn;                         // h(t+2) -> A0
            pchain(ax, wx, biasv, P);                    // P for t+2 (shadow)
        }
    }
    // after loop: H_0 (encoder final h) in A0.

    // ================= decoder setup =================
    // x_last into register BEFORE predbuf aliases xs (row Tt-1 is outside the
    // 8 KB alias anyway, but register-hoisting keeps the chain clean).
    half8 axl = *(const half8*)(xs + (Tt - 1) * XSTRIDE + (col >> 2) * 8);

    // Plain decoder weights (step 0 only) + folded weights W' (steps 1..63).
    half8 wp0[4], wp1[4];
    f32x4 biasp[4];
    #pragma unroll
    for (int Tg = 0; Tg < 4; ++Tg) {
        int g = Tg * 64 + u;
        float sc = (Tg == 2) ? K2LOG2 : LOG2E;
        #pragma unroll
        for (int j = 0; j < 8; ++j) {
            int k0 = q * 8 + j;
            float v0 = dWhh[g * 64 + k0];
            float v1 = dWhh[g * 64 + 32 + k0];
            w0[Tg][j] = (_Float16)(v0 * sc);             // plain (step 0)
            w1[Tg][j] = (_Float16)(v1 * sc);
            wx[Tg][j] = (q == 0) ? (_Float16)(dWih[g * 8 + j] * sc) : (_Float16)0.f;
            float s0 = v0, s1 = v1;                      // fold: W' = Whh + Wih*fcW
            #pragma unroll
            for (int f = 0; f < 8; ++f) {
                float wif = dWih[g * 8 + f];
                s0 = __builtin_fmaf(wif, fcW[f * 64 + k0], s0);
                s1 = __builtin_fmaf(wif, fcW[f * 64 + 32 + k0], s1);
            }
            wp0[Tg][j] = (_Float16)(s0 * sc);
            wp1[Tg][j] = (_Float16)(s1 * sc);
        }
        float bb = dbih[g] + dbhh[g];
        float bp = bb;                                   // b' = b + Wih*fcb
        #pragma unroll
        for (int f = 0; f < 8; ++f) bp = __builtin_fmaf(dWih[g * 8 + f], fcb[f], bp);
        biasv[Tg] = (f32x4){bb * sc, bb * sc, bb * sc, bb * sc};
        biasp[Tg] = (f32x4){bp * sc, bp * sc, bp * sc, bp * sc};
    }
    // fc fragments: pred[b][f] = sum_u h[b][u]*fcW[f][u] + fcb[f]
    half8 wf0, wf1;
    f32x4 biasf;
    {
        #pragma unroll
        for (int j = 0; j < 8; ++j) {
            wf0[j] = (col < 8) ? (_Float16)fcW[col * 64 + q * 8 + j]      : (_Float16)0.f;
            wf1[j] = (col < 8) ? (_Float16)fcW[col * 64 + 32 + q * 8 + j] : (_Float16)0.f;
        }
        float fb = (col < 8) ? fcb[col] : 0.f;
        biasf = (f32x4){fb, fb, fb, fb};
    }

    float* predbuf = (float*)xs;                         // 8 KB alias over dead xs
    const bool pw = (wv == 0) && (col < 8);              // pred writer lanes

    // ---- decoder step 0: plain path, x = x_last ----
    __syncthreads();                                     // H_0 visible (A0)
    {
        half8 a0 = *(const half8*)(arA);
        half8 a1 = *(const half8*)(arA + 32);
        pchain(axl, wx, biasv, P);
        float hn = qcell(a0, a1, w0, w1, P, cS);
        *hwB = (_Float16)hn;                             // H_1 -> A1
    }

    // ---- decoder steps 1..63: pure h-recurrence (folded W'), pred in shadow ----
    for (int p = 1; p < Pp; ++p) {
        __syncthreads();                                 // H_p visible
        const _Float16* ar = (p & 1) ? arB : arA;
        _Float16*       hw = (p & 1) ? hwA : hwB;
        half8 a0 = *(const half8*)(ar);
        half8 a1 = *(const half8*)(ar + 32);
        float hn = qcell(a0, a1, wp0, wp1, biasp, cS);   // CP: same as encoder
        *hw = (_Float16)hn;                              // H_{p+1}
        // shadow: pred(p-1) = fc(H_p) via 2 MFMAs, off the chain
        f32x4 F = __builtin_amdgcn_mfma_f32_16x16x32_f16(a0, wf0, biasf, 0, 0, 0);
        F       = __builtin_amdgcn_mfma_f32_16x16x32_f16(a1, wf1, F,     0, 0, 0);
        if (pw) predbuf[q * (Pp * Ff) + (p - 1) * Ff + col] = F[0];
    }

    // ---- epilogue: pred(63) = fc(H_64) (H_64 in A0: p=63 odd wrote hwA) ----
    __syncthreads();
    {
        half8 a0 = *(const half8*)(arA);
        half8 a1 = *(const half8*)(arA + 32);
        f32x4 F = __builtin_amdgcn_mfma_f32_16x16x32_f16(a0, wf0, biasf, 0, 0, 0);
        F       = __builtin_amdgcn_mfma_f32_16x16x32_f16(a1, wf1, F,     0, 0, 0);
        if (pw) predbuf[q * (Pp * Ff) + (Pp - 1) * Ff + col] = F[0];
    }
    __syncthreads();

    // ================= flush preds: LDS -> global, coalesced float4 =================
    {
        f32x4* out4 = (f32x4*)out + (size_t)b0 * (Pp * Ff / 4);
        const f32x4* pb4 = (const f32x4*)predbuf;
        for (int i = tid; i < MB * Pp * Ff / 4; i += 256)
            out4[i] = pb4[i];
    }
}

extern "C" void kernel_launch(void* const* d_in, const int* in_sizes, int n_in,
                              void* d_out, int out_size, void* d_ws, size_t ws_size,
                              hipStream_t stream) {
    (void)in_sizes; (void)n_in; (void)d_ws; (void)ws_size; (void)out_size;
    hipLaunchKernelGGL(seq2seq_v12, dim3(NBLK), dim3(256), 0, stream,
                       (const float*)d_in[0],
                       (const float*)d_in[1], (const float*)d_in[2],
                       (const float*)d_in[3], (const float*)d_in[4],
                       (const float*)d_in[5], (const float*)d_in[6],
                       (const float*)d_in[7], (const float*)d_in[8],
                       (const float*)d_in[9], (const float*)d_in[10],
                       (float*)d_out);
}